// Round 2
// baseline (290.495 us; speedup 1.0000x reference)
//
#include <hip/hip_runtime.h>
#include <hip/hip_bf16.h>

// FrequencyLayer: separable real DFT via bf16 MFMA.
// real[b,c,u,v] = sum_{i,j} x[i,j] cos(2pi(j*u+i*v)/N)
// imag[b,c,u,v] = -sum_{i,j} x[i,j] sin(2pi(j*u+i*v)/N), N=256, u,v in [0,128)
//
// v2: 512-thread blocks (16 waves/CU, was 8), up-loop merged (X read 2x not 4x),
// b64 LDS writes via MFMA operand swap, h-halves split into paired blocks with
// XCD-affinity swizzle so the h=1 re-read of X hits the same XCD's L2.
// v2.1: rename short4 -> bf16x4 (HIP predefines short4 as HIP_vector_type).

typedef __attribute__((ext_vector_type(8))) short short8;   // 8 bf16 = 4 VGPR (MFMA A/B frag)
typedef __attribute__((ext_vector_type(4))) short bf16x4;   // 4 bf16 = 8B (ds_write_b64)
typedef __attribute__((ext_vector_type(4))) float f32x4;    // MFMA C/D frag

#define NN 256
#define KF 128
#define NIMG 1024

__device__ __align__(16) short g_Ct[KF * NN];   // cos(2pi*u*j/256)
__device__ __align__(16) short g_St[KF * NN];   // sin(2pi*u*j/256)
__device__ __align__(16) short g_Stn[KF * NN];  // -sin(2pi*u*j/256)

__device__ __forceinline__ short f2bf(float f) {
    union { float f; unsigned u; } v; v.f = f;
    unsigned r = v.u + 0x7FFFu + ((v.u >> 16) & 1u);  // RNE
    return (short)(r >> 16);
}

__global__ void gen_tables() {
    int tid = blockIdx.x * blockDim.x + threadIdx.x;
    if (tid >= KF * NN) return;
    int u = tid >> 8;
    int j = tid & 255;
    int phase = (u * j) & 255;                       // exploit periodicity, exact angle
    float ang = (float)phase * 0.02454369260617026f; // 2pi/256
    float s, c;
    sincosf(ang, &s, &c);
    g_Ct[tid]  = f2bf(c);
    g_St[tid]  = f2bf(s);
    g_Stn[tid] = f2bf(-s);
}

__global__ __launch_bounds__(512, 4) void freq_dft(const float* __restrict__ x,
                                                   float* __restrict__ out) {
    // LDS: A1T (64 rows x 256 cols bf16, 32KB) | B1n (32KB). XOR-swizzled rows.
    __shared__ __align__(16) char lds[65536];

    // XCD-pairing decode: both h-half blocks of one image get bids differing by 8
    // -> same XCD (bid%8), adjacent in that XCD's queue -> h=1 X re-read is L2-hot.
    const int bid = blockIdx.x;
    const int c   = bid & 7;
    const int q   = bid >> 3;
    const int h   = q & 1;
    const int img = c + ((q >> 1) << 3);

    const float* __restrict__ X = x + (size_t)img * (NN * NN);
    float* __restrict__ outR = out + (size_t)img * (KF * KF);
    float* __restrict__ outI = outR + (size_t)NIMG * (KF * KF);

    const int lane = threadIdx.x & 63;
    const int wave = threadIdx.x >> 6;   // 0..7
    const int l15  = lane & 15;
    const int lk8  = (lane >> 4) << 3;   // A/B frag k-base
    const int lr4  = (lane >> 4) << 2;   // D frag row-base

    // ---------------- stage 1: A1T/B1n[u in half][i in 0..256) ----------------
    {
        const int i0 = wave * 32;        // this wave's i-slice (32 rows)
        const int u0 = h * 64;
        f32x4 accA[2][4], accB[2][4];    // [fi][fu] : D[i][u] fragments
        #pragma unroll
        for (int fi = 0; fi < 2; ++fi)
            #pragma unroll
            for (int fu = 0; fu < 4; ++fu) {
                accA[fi][fu] = (f32x4){0.f, 0.f, 0.f, 0.f};
                accB[fi][fu] = (f32x4){0.f, 0.f, 0.f, 0.f};
            }
        for (int j0 = 0; j0 < NN; j0 += 32) {
            short8 xb[2];
            #pragma unroll
            for (int fi = 0; fi < 2; ++fi) {
                const float* p = X + ((i0 + fi * 16 + l15) * NN + j0 + lk8);
                f32x4 p0 = *(const f32x4*)p;
                f32x4 p1 = *(const f32x4*)(p + 4);
                short8 t;
                t[0] = f2bf(p0[0]); t[1] = f2bf(p0[1]); t[2] = f2bf(p0[2]); t[3] = f2bf(p0[3]);
                t[4] = f2bf(p1[0]); t[5] = f2bf(p1[1]); t[6] = f2bf(p1[2]); t[7] = f2bf(p1[3]);
                xb[fi] = t;
            }
            #pragma unroll
            for (int fu = 0; fu < 4; ++fu) {
                int off = (u0 + fu * 16 + l15) * NN + j0 + lk8;
                short8 ca = *(const short8*)(&g_Ct[off]);
                short8 sa = *(const short8*)(&g_Stn[off]);
                // A-operand = X (rows i), B-operand = Ct^T (cols u):
                // D row = i (4 consecutive per lane), D col = u.
                accA[0][fu] = __builtin_amdgcn_mfma_f32_16x16x32_bf16(xb[0], ca, accA[0][fu], 0, 0, 0);
                accA[1][fu] = __builtin_amdgcn_mfma_f32_16x16x32_bf16(xb[1], ca, accA[1][fu], 0, 0, 0);
                accB[0][fu] = __builtin_amdgcn_mfma_f32_16x16x32_bf16(xb[0], sa, accB[0][fu], 0, 0, 0);
                accB[1][fu] = __builtin_amdgcn_mfma_f32_16x16x32_bf16(xb[1], sa, accB[1][fu], 0, 0, 0);
            }
        }
        // D-frag: col = u local (l15), rows = 4 consecutive i -> one b64 write each.
        #pragma unroll
        for (int fi = 0; fi < 2; ++fi)
            #pragma unroll
            for (int fu = 0; fu < 4; ++fu) {
                int ul = fu * 16 + l15;              // local u row 0..63
                int ibase = i0 + fi * 16 + lr4;      // 4 consecutive i from here
                int byte = ul * 512 + ((ibase * 2) ^ ((ul & 7) << 4));
                bf16x4 a4, b4;
                #pragma unroll
                for (int r = 0; r < 4; ++r) {
                    a4[r] = f2bf(accA[fi][fu][r]);
                    b4[r] = f2bf(accB[fi][fu][r]);
                }
                *(bf16x4*)(lds + byte)         = a4;
                *(bf16x4*)(lds + 32768 + byte) = b4;
            }
    }
    __syncthreads();
    // ---------------- stage 2: real/imag[u in half][all v] ----------------
    {
        const int wu = wave >> 2;        // 0..1 : u-slice of 32 within the half
        const int wv = wave & 3;         // 0..3 : v-slice of 32
        f32x4 accR[2][2], accI[2][2];    // [fu][fv]
        #pragma unroll
        for (int fu = 0; fu < 2; ++fu)
            #pragma unroll
            for (int fv = 0; fv < 2; ++fv) {
                accR[fu][fv] = (f32x4){0.f, 0.f, 0.f, 0.f};
                accI[fu][fv] = (f32x4){0.f, 0.f, 0.f, 0.f};
            }
        for (int is = 0; is < NN; is += 32) {
            short8 a[2], bn[2];
            #pragma unroll
            for (int fu = 0; fu < 2; ++fu) {
                int ul = wu * 32 + fu * 16 + l15;
                int byte = ul * 512 + (((is + lk8) * 2) ^ ((ul & 7) << 4));
                a[fu]  = *(const short8*)(lds + byte);
                bn[fu] = *(const short8*)(lds + 32768 + byte);
            }
            short8 cb[2], sb[2], nb[2];
            #pragma unroll
            for (int fv = 0; fv < 2; ++fv) {
                int off = (wv * 32 + fv * 16 + l15) * NN + is + lk8;
                cb[fv] = *(const short8*)(&g_Ct[off]);
                sb[fv] = *(const short8*)(&g_St[off]);
                nb[fv] = *(const short8*)(&g_Stn[off]);
            }
            #pragma unroll
            for (int fu = 0; fu < 2; ++fu)
                #pragma unroll
                for (int fv = 0; fv < 2; ++fv) {
                    accR[fu][fv] = __builtin_amdgcn_mfma_f32_16x16x32_bf16(a[fu],  cb[fv], accR[fu][fv], 0, 0, 0);
                    accR[fu][fv] = __builtin_amdgcn_mfma_f32_16x16x32_bf16(bn[fu], sb[fv], accR[fu][fv], 0, 0, 0);
                    accI[fu][fv] = __builtin_amdgcn_mfma_f32_16x16x32_bf16(bn[fu], cb[fv], accI[fu][fv], 0, 0, 0);
                    accI[fu][fv] = __builtin_amdgcn_mfma_f32_16x16x32_bf16(a[fu],  nb[fv], accI[fu][fv], 0, 0, 0);
                }
        }
        #pragma unroll
        for (int fu = 0; fu < 2; ++fu)
            #pragma unroll
            for (int fv = 0; fv < 2; ++fv)
                #pragma unroll
                for (int r = 0; r < 4; ++r) {
                    int u = h * 64 + wu * 32 + fu * 16 + lr4 + r;
                    int v = wv * 32 + fv * 16 + l15;
                    outR[u * KF + v] = accR[fu][fv][r];
                    outI[u * KF + v] = accI[fu][fv][r];
                }
    }
}

extern "C" void kernel_launch(void* const* d_in, const int* in_sizes, int n_in,
                              void* d_out, int out_size, void* d_ws, size_t ws_size,
                              hipStream_t stream) {
    const float* x = (const float*)d_in[0];
    float* out = (float*)d_out;
    gen_tables<<<dim3((KF * NN + 255) / 256), dim3(256), 0, stream>>>();
    freq_dft<<<dim3(NIMG * 2), dim3(512), 0, stream>>>(x, out);
}

// Round 3
// 193.136 us; speedup vs baseline: 1.5041x; 1.5041x over previous
//
#include <hip/hip_runtime.h>
#include <hip/hip_bf16.h>

// FrequencyLayer: separable real DFT via bf16 MFMA.
// real[b,c,u,v] = sum_{i,j} x[i,j] cos(2pi(j*u+i*v)/N)
// imag[b,c,u,v] = -sum_{i,j} x[i,j] sin(2pi(j*u+i*v)/N), N=256, u,v in [0,128)
//
// v3: attack inner-loop load serialization (v2 showed all pipes <10% busy):
//  - stage-1 tables staged once into LDS (swizzled), reused by all 8 waves
//  - X prefetched 1 j-iter ahead in f32 regs, converted at consume
//  - stage-2 tables prefetched 1 k-iter ahead in regs
//  - LDS table region reused for A1T/B1n after stage 1 (still 64KB -> 2 blocks/CU)

typedef __attribute__((ext_vector_type(8))) short short8;   // 8 bf16 = 4 VGPR (MFMA A/B frag)
typedef __attribute__((ext_vector_type(4))) short bf16x4;   // 4 bf16 = 8B (ds_write_b64)
typedef __attribute__((ext_vector_type(4))) float f32x4;    // MFMA C/D frag

#define NN 256
#define KF 128
#define NIMG 1024

__device__ __align__(16) short g_Ct[KF * NN];   // cos(2pi*u*j/256)
__device__ __align__(16) short g_St[KF * NN];   // sin(2pi*u*j/256)
__device__ __align__(16) short g_Stn[KF * NN];  // -sin(2pi*u*j/256)

__device__ __forceinline__ short f2bf(float f) {
    union { float f; unsigned u; } v; v.f = f;
    unsigned r = v.u + 0x7FFFu + ((v.u >> 16) & 1u);  // RNE
    return (short)(r >> 16);
}

__global__ void gen_tables() {
    int tid = blockIdx.x * blockDim.x + threadIdx.x;
    if (tid >= KF * NN) return;
    int u = tid >> 8;
    int j = tid & 255;
    int phase = (u * j) & 255;                       // exploit periodicity, exact angle
    float ang = (float)phase * 0.02454369260617026f; // 2pi/256
    float s, c;
    sincosf(ang, &s, &c);
    g_Ct[tid]  = f2bf(c);
    g_St[tid]  = f2bf(s);
    g_Stn[tid] = f2bf(-s);
}

#define MFMA(a, b, c) __builtin_amdgcn_mfma_f32_16x16x32_bf16(a, b, c, 0, 0, 0)

__global__ __launch_bounds__(512, 4) void freq_dft(const float* __restrict__ x,
                                                   float* __restrict__ out) {
    // LDS (64KB), two lifetimes:
    //   phase A/B: Ct half-slice [64][256] bf16 swizzled (32KB) | Stn half-slice (32KB)
    //   phase C/D: A1T [64u][256i] bf16 swizzled (32KB) | B1n (32KB)
    __shared__ __align__(16) char lds[65536];

    // XCD-pairing decode: both h-half blocks of one image land on the same XCD.
    const int bid = blockIdx.x;
    const int cc  = bid & 7;
    const int q   = bid >> 3;
    const int h   = q & 1;
    const int img = cc + ((q >> 1) << 3);

    const float* __restrict__ X = x + (size_t)img * (NN * NN);
    float* __restrict__ outR = out + (size_t)img * (KF * KF);
    float* __restrict__ outI = outR + (size_t)NIMG * (KF * KF);

    const int lane = threadIdx.x & 63;
    const int wave = threadIdx.x >> 6;   // 0..7
    const int l15  = lane & 15;
    const int lk8  = (lane >> 4) << 3;   // A/B frag k-base (shorts)
    const int lr4  = (lane >> 4) << 2;   // D frag row-base

    // ---------------- phase A: tables -> LDS (swizzled write, linear global read) ----
    {
        const short* __restrict__ srcC = g_Ct  + h * 64 * NN;
        const short* __restrict__ srcS = g_Stn + h * 64 * NN;
        #pragma unroll
        for (int k = 0; k < 4; ++k) {
            int slot = threadIdx.x + k * 512;        // 16B-chunk index, 0..2047
            int row  = slot >> 5;                    // 0..63
            int chk  = slot & 31;                    // 16B chunk within row
            int byte = row * 512 + ((chk << 4) ^ ((row & 7) << 4));
            short8 vC = *(const short8*)(srcC + row * NN + chk * 8);
            short8 vS = *(const short8*)(srcS + row * NN + chk * 8);
            *(short8*)(lds + byte)         = vC;
            *(short8*)(lds + 32768 + byte) = vS;
        }
    }
    __syncthreads();

    // ---------------- phase B: stage 1, X prefetched, tables from LDS --------------
    f32x4 accA[2][4], accB[2][4];    // [fi][fu] : D[i][u] fragments
    {
        const int i0 = wave * 32;    // this wave's i-slice (32 rows)
        #pragma unroll
        for (int fi = 0; fi < 2; ++fi)
            #pragma unroll
            for (int fu = 0; fu < 4; ++fu) {
                accA[fi][fu] = (f32x4){0.f, 0.f, 0.f, 0.f};
                accB[fi][fu] = (f32x4){0.f, 0.f, 0.f, 0.f};
            }
        const float* __restrict__ xp0 = X + (i0 + l15) * NN + lk8;
        const float* __restrict__ xp1 = X + (i0 + 16 + l15) * NN + lk8;
        f32x4 nx0 = *(const f32x4*)(xp0);
        f32x4 nx1 = *(const f32x4*)(xp0 + 4);
        f32x4 nx2 = *(const f32x4*)(xp1);
        f32x4 nx3 = *(const f32x4*)(xp1 + 4);
        #pragma unroll
        for (int jj = 0; jj < 8; ++jj) {
            const int j0 = jj * 32;
            f32x4 c0 = nx0, c1 = nx1, c2 = nx2, c3 = nx3;
            if (jj < 7) {   // prefetch next j-tile (issues before current compute)
                nx0 = *(const f32x4*)(xp0 + j0 + 32);
                nx1 = *(const f32x4*)(xp0 + j0 + 36);
                nx2 = *(const f32x4*)(xp1 + j0 + 32);
                nx3 = *(const f32x4*)(xp1 + j0 + 36);
            }
            short8 xb0, xb1;
            xb0[0] = f2bf(c0[0]); xb0[1] = f2bf(c0[1]); xb0[2] = f2bf(c0[2]); xb0[3] = f2bf(c0[3]);
            xb0[4] = f2bf(c1[0]); xb0[5] = f2bf(c1[1]); xb0[6] = f2bf(c1[2]); xb0[7] = f2bf(c1[3]);
            xb1[0] = f2bf(c2[0]); xb1[1] = f2bf(c2[1]); xb1[2] = f2bf(c2[2]); xb1[3] = f2bf(c2[3]);
            xb1[4] = f2bf(c3[0]); xb1[5] = f2bf(c3[1]); xb1[6] = f2bf(c3[2]); xb1[7] = f2bf(c3[3]);
            short8 ca[4], sa[4];
            #pragma unroll
            for (int fu = 0; fu < 4; ++fu) {
                int row  = fu * 16 + l15;
                int byte = row * 512 + (((j0 + lk8) * 2) ^ ((row & 7) << 4));
                ca[fu] = *(const short8*)(lds + byte);
                sa[fu] = *(const short8*)(lds + 32768 + byte);
            }
            #pragma unroll
            for (int fu = 0; fu < 4; ++fu) {
                accA[0][fu] = MFMA(xb0, ca[fu], accA[0][fu]);
                accA[1][fu] = MFMA(xb1, ca[fu], accA[1][fu]);
                accB[0][fu] = MFMA(xb0, sa[fu], accB[0][fu]);
                accB[1][fu] = MFMA(xb1, sa[fu], accB[1][fu]);
            }
        }
    }
    __syncthreads();   // all table reads done; LDS region can be overwritten

    // ---------------- phase C: A1T/B1n -> LDS (b64 writes, swizzled rows) ----------
    {
        const int i0 = wave * 32;
        #pragma unroll
        for (int fi = 0; fi < 2; ++fi)
            #pragma unroll
            for (int fu = 0; fu < 4; ++fu) {
                int ul    = fu * 16 + l15;           // local u row 0..63
                int ibase = i0 + fi * 16 + lr4;      // 4 consecutive i
                int byte  = ul * 512 + ((ibase * 2) ^ ((ul & 7) << 4));
                bf16x4 a4, b4;
                #pragma unroll
                for (int r = 0; r < 4; ++r) {
                    a4[r] = f2bf(accA[fi][fu][r]);
                    b4[r] = f2bf(accB[fi][fu][r]);
                }
                *(bf16x4*)(lds + byte)         = a4;
                *(bf16x4*)(lds + 32768 + byte) = b4;
            }
    }
    __syncthreads();

    // ---------------- phase D: stage 2, tables prefetched from global --------------
    {
        const int wu = wave >> 2;        // 0..1 : u-slice of 32 within the half
        const int wv = wave & 3;         // 0..3 : v-slice of 32
        f32x4 accR[2][2], accI[2][2];    // [fu][fv]
        #pragma unroll
        for (int fu = 0; fu < 2; ++fu)
            #pragma unroll
            for (int fv = 0; fv < 2; ++fv) {
                accR[fu][fv] = (f32x4){0.f, 0.f, 0.f, 0.f};
                accI[fu][fv] = (f32x4){0.f, 0.f, 0.f, 0.f};
            }
        const short* __restrict__ tC0 = g_Ct  + (wv * 32 + l15) * NN + lk8;
        const short* __restrict__ tC1 = g_Ct  + (wv * 32 + 16 + l15) * NN + lk8;
        const short* __restrict__ tS0 = g_St  + (wv * 32 + l15) * NN + lk8;
        const short* __restrict__ tS1 = g_St  + (wv * 32 + 16 + l15) * NN + lk8;
        const short* __restrict__ tN0 = g_Stn + (wv * 32 + l15) * NN + lk8;
        const short* __restrict__ tN1 = g_Stn + (wv * 32 + 16 + l15) * NN + lk8;
        short8 cbN0 = *(const short8*)tC0, cbN1 = *(const short8*)tC1;
        short8 sbN0 = *(const short8*)tS0, sbN1 = *(const short8*)tS1;
        short8 nbN0 = *(const short8*)tN0, nbN1 = *(const short8*)tN1;
        #pragma unroll
        for (int ii = 0; ii < 8; ++ii) {
            const int is = ii * 32;
            short8 cb0 = cbN0, cb1 = cbN1, sb0 = sbN0, sb1 = sbN1, nb0 = nbN0, nb1 = nbN1;
            if (ii < 7) {   // prefetch next k-tile's table fragments
                cbN0 = *(const short8*)(tC0 + is + 32);
                cbN1 = *(const short8*)(tC1 + is + 32);
                sbN0 = *(const short8*)(tS0 + is + 32);
                sbN1 = *(const short8*)(tS1 + is + 32);
                nbN0 = *(const short8*)(tN0 + is + 32);
                nbN1 = *(const short8*)(tN1 + is + 32);
            }
            short8 a[2], bn[2];
            #pragma unroll
            for (int fu = 0; fu < 2; ++fu) {
                int ul   = wu * 32 + fu * 16 + l15;
                int byte = ul * 512 + (((is + lk8) * 2) ^ ((ul & 7) << 4));
                a[fu]  = *(const short8*)(lds + byte);
                bn[fu] = *(const short8*)(lds + 32768 + byte);
            }
            accR[0][0] = MFMA(a[0],  cb0, accR[0][0]);
            accR[0][1] = MFMA(a[0],  cb1, accR[0][1]);
            accR[1][0] = MFMA(a[1],  cb0, accR[1][0]);
            accR[1][1] = MFMA(a[1],  cb1, accR[1][1]);
            accR[0][0] = MFMA(bn[0], sb0, accR[0][0]);
            accR[0][1] = MFMA(bn[0], sb1, accR[0][1]);
            accR[1][0] = MFMA(bn[1], sb0, accR[1][0]);
            accR[1][1] = MFMA(bn[1], sb1, accR[1][1]);
            accI[0][0] = MFMA(bn[0], cb0, accI[0][0]);
            accI[0][1] = MFMA(bn[0], cb1, accI[0][1]);
            accI[1][0] = MFMA(bn[1], cb0, accI[1][0]);
            accI[1][1] = MFMA(bn[1], cb1, accI[1][1]);
            accI[0][0] = MFMA(a[0],  nb0, accI[0][0]);
            accI[0][1] = MFMA(a[0],  nb1, accI[0][1]);
            accI[1][0] = MFMA(a[1],  nb0, accI[1][0]);
            accI[1][1] = MFMA(a[1],  nb1, accI[1][1]);
        }
        #pragma unroll
        for (int fu = 0; fu < 2; ++fu)
            #pragma unroll
            for (int fv = 0; fv < 2; ++fv)
                #pragma unroll
                for (int r = 0; r < 4; ++r) {
                    int u = h * 64 + wu * 32 + fu * 16 + lr4 + r;
                    int v = wv * 32 + fv * 16 + l15;
                    outR[u * KF + v] = accR[fu][fv][r];
                    outI[u * KF + v] = accI[fu][fv][r];
                }
    }
}

extern "C" void kernel_launch(void* const* d_in, const int* in_sizes, int n_in,
                              void* d_out, int out_size, void* d_ws, size_t ws_size,
                              hipStream_t stream) {
    const float* x = (const float*)d_in[0];
    float* out = (float*)d_out;
    gen_tables<<<dim3((KF * NN + 255) / 256), dim3(256), 0, stream>>>();
    freq_dft<<<dim3(NIMG * 2), dim3(512), 0, stream>>>(x, out);
}